// Round 1
// baseline (196.140 us; speedup 1.0000x reference)
//
#include <hip/hip_runtime.h>

#define NN 4096
#define DD 2048
#define MARGIN_F 0.3f

typedef __attribute__((ext_vector_type(8))) short bf16x8;
typedef __attribute__((ext_vector_type(4))) float f32x4;

__device__ __forceinline__ unsigned short f2bf(float f) {
    union { float f; unsigned u; } cv; cv.f = f;
    unsigned u = cv.u;
    // round-to-nearest-even (inputs are finite, no NaN handling needed)
    return (unsigned short)((u + 0x7FFFu + ((u >> 16) & 1u)) >> 16);
}

// One block per row: compute fp32 sum-of-squares, write bf16 copy of the row,
// and initialize the per-row ap/an reduction cells (ws is poisoned each call).
__global__ __launch_bounds__(256) void prep_kernel(const float* __restrict__ x,
                                                   unsigned short* __restrict__ xb,
                                                   float* __restrict__ sq,
                                                   unsigned int* __restrict__ ap,
                                                   unsigned int* __restrict__ an) {
    const int row = blockIdx.x;
    const int t = threadIdx.x;
    const float* xr = x + (size_t)row * DD;
    float4 v0 = ((const float4*)xr)[2 * t];
    float4 v1 = ((const float4*)xr)[2 * t + 1];
    float s = v0.x * v0.x + v0.y * v0.y + v0.z * v0.z + v0.w * v0.w +
              v1.x * v1.x + v1.y * v1.y + v1.z * v1.z + v1.w * v1.w;
    ushort4 o0, o1;
    o0.x = f2bf(v0.x); o0.y = f2bf(v0.y); o0.z = f2bf(v0.z); o0.w = f2bf(v0.w);
    o1.x = f2bf(v1.x); o1.y = f2bf(v1.y); o1.z = f2bf(v1.z); o1.w = f2bf(v1.w);
    ushort4* xo = (ushort4*)(xb + (size_t)row * DD);
    xo[2 * t] = o0;
    xo[2 * t + 1] = o1;

    // block reduction of sum of squares
    for (int off = 32; off > 0; off >>= 1) s += __shfl_down(s, off, 64);
    __shared__ float wsum[4];
    const int wave = t >> 6, lane = t & 63;
    if (lane == 0) wsum[wave] = s;
    __syncthreads();
    if (t == 0) {
        sq[row] = wsum[0] + wsum[1] + wsum[2] + wsum[3];
        ap[row] = 0u;            // max over positives starts at 0 (matches ref where())
        an[row] = 0x7F800000u;   // +inf
    }
}

// 128x128 tile of S = Xb * Xb^T, m97 structure (BK=32, global_load_lds w=16,
// 4 waves as 2x2 of 64x64, 4x4 frags of mfma 16x16x32 bf16). Epilogue converts
// dot -> dist, does masked max/min over the tile's 128 columns per row, and
// folds into global ap/an via uint atomics (valid: all dists >= 0).
__global__ __launch_bounds__(256) void gemm_reduce_kernel(
    const unsigned short* __restrict__ xb,
    const float* __restrict__ sq,
    const int* __restrict__ labels,
    unsigned int* __restrict__ ap,
    unsigned int* __restrict__ an) {
    __shared__ __align__(16) unsigned short As[128 * 32];
    __shared__ __align__(16) unsigned short Bs[128 * 32];

    const int t = threadIdx.x;
    const int lane = t & 63;
    const int wave = t >> 6;
    const int c = lane & 15;   // col within 16-tile / fragment lane col
    const int q = lane >> 4;   // quad id
    const int wr = (wave >> 1) * 64;  // wave row offset in tile
    const int wc = (wave & 1) * 64;   // wave col offset in tile
    const int row0 = blockIdx.y * 128;
    const int col0 = blockIdx.x * 128;

    f32x4 acc[4][4];
#pragma unroll
    for (int mi = 0; mi < 4; ++mi)
#pragma unroll
        for (int ni = 0; ni < 4; ++ni)
            acc[mi][ni] = (f32x4){0.f, 0.f, 0.f, 0.f};

    // staging chunks: 512 x 16B per 8KB tile; thread t takes chunks t and t+256.
    // LDS dest = wave-uniform base + lane*16 (required by global_load_lds).
    const int ca0 = t, ca1 = t + 256;
    const unsigned short* gA0 = xb + (size_t)(row0 + (ca0 >> 2)) * DD + (ca0 & 3) * 8;
    const unsigned short* gA1 = xb + (size_t)(row0 + (ca1 >> 2)) * DD + (ca1 & 3) * 8;
    const unsigned short* gB0 = xb + (size_t)(col0 + (ca0 >> 2)) * DD + (ca0 & 3) * 8;
    const unsigned short* gB1 = xb + (size_t)(col0 + (ca1 >> 2)) * DD + (ca1 & 3) * 8;
    unsigned short* lA0 = &As[ca0 * 8];
    unsigned short* lA1 = &As[ca1 * 8];
    unsigned short* lB0 = &Bs[ca0 * 8];
    unsigned short* lB1 = &Bs[ca1 * 8];

    for (int k0 = 0; k0 < DD; k0 += 32) {
        __builtin_amdgcn_global_load_lds(
            (const __attribute__((address_space(1))) void*)(gA0 + k0),
            (__attribute__((address_space(3))) void*)lA0, 16, 0, 0);
        __builtin_amdgcn_global_load_lds(
            (const __attribute__((address_space(1))) void*)(gA1 + k0),
            (__attribute__((address_space(3))) void*)lA1, 16, 0, 0);
        __builtin_amdgcn_global_load_lds(
            (const __attribute__((address_space(1))) void*)(gB0 + k0),
            (__attribute__((address_space(3))) void*)lB0, 16, 0, 0);
        __builtin_amdgcn_global_load_lds(
            (const __attribute__((address_space(1))) void*)(gB1 + k0),
            (__attribute__((address_space(3))) void*)lB1, 16, 0, 0);
        __syncthreads();  // drains vmcnt -> LDS tiles ready

        const bf16x8* Av = (const bf16x8*)As;
        const bf16x8* Bv = (const bf16x8*)Bs;
        bf16x8 af[4], bfr[4];
#pragma unroll
        for (int mi = 0; mi < 4; ++mi) af[mi] = Av[(wr + mi * 16 + c) * 4 + q];
#pragma unroll
        for (int ni = 0; ni < 4; ++ni) bfr[ni] = Bv[(wc + ni * 16 + c) * 4 + q];
#pragma unroll
        for (int mi = 0; mi < 4; ++mi)
#pragma unroll
            for (int ni = 0; ni < 4; ++ni)
                acc[mi][ni] = __builtin_amdgcn_mfma_f32_16x16x32_bf16(
                    af[mi], bfr[ni], acc[mi][ni], 0, 0, 0);
        __syncthreads();  // all waves done reading LDS before next stage
    }

    // Epilogue: dot -> dist; masked max/min over this tile's columns.
    // C/D layout: col = lane&15, row = (lane>>4)*4 + reg  [m89/m91 verified]
    float sq_col[4];
    int lab_col[4];
#pragma unroll
    for (int ni = 0; ni < 4; ++ni) {
        const int gj = col0 + wc + ni * 16 + c;
        sq_col[ni] = sq[gj];
        lab_col[ni] = labels[gj];
    }
#pragma unroll
    for (int mi = 0; mi < 4; ++mi) {
#pragma unroll
        for (int r = 0; r < 4; ++r) {
            const int gi = row0 + wr + mi * 16 + q * 4 + r;
            const float sqi = sq[gi];
            const int li = labels[gi];
            float apm = 0.0f;
            float anm = __builtin_inff();
#pragma unroll
            for (int ni = 0; ni < 4; ++ni) {
                const int gj = col0 + wc + ni * 16 + c;
                const float dot = acc[mi][ni][r];
                float d2 = sqi + sq_col[ni] - 2.0f * dot;
                d2 = fmaxf(d2, 0.0f);
                const float dist = sqrtf(d2);
                if (li == lab_col[ni]) {
                    if (gi != gj) apm = fmaxf(apm, dist);  // diagonal excluded (ref has 0)
                } else {
                    anm = fminf(anm, dist);
                }
            }
            // reduce across the 16 lanes holding this row's columns
#pragma unroll
            for (int off = 1; off < 16; off <<= 1) {
                apm = fmaxf(apm, __shfl_xor(apm, off, 16));
                anm = fminf(anm, __shfl_xor(anm, off, 16));
            }
            if (c == 0) {
                atomicMax(&ap[gi], __float_as_uint(apm));
                atomicMin(&an[gi], __float_as_uint(anm));
            }
        }
    }
}

__global__ __launch_bounds__(256) void finalize_kernel(const unsigned int* __restrict__ ap,
                                                       const unsigned int* __restrict__ an,
                                                       float* __restrict__ out) {
    float sum = 0.0f;
    int cnt = 0;
    for (int i = threadIdx.x; i < NN; i += 256) {
        const float a = __uint_as_float(ap[i]);
        const float b = __uint_as_float(an[i]);
        const bool valid = (a > 0.0f) && (b < __builtin_inff());
        if (valid) {
            sum += fmaxf(a - b + MARGIN_F, 0.0f);
            cnt += 1;
        }
    }
    for (int off = 32; off > 0; off >>= 1) {
        sum += __shfl_down(sum, off, 64);
        cnt += __shfl_down(cnt, off, 64);
    }
    __shared__ float ssum[4];
    __shared__ int scnt[4];
    const int wave = threadIdx.x >> 6, lane = threadIdx.x & 63;
    if (lane == 0) { ssum[wave] = sum; scnt[wave] = cnt; }
    __syncthreads();
    if (threadIdx.x == 0) {
        float s = ssum[0] + ssum[1] + ssum[2] + ssum[3];
        int n = scnt[0] + scnt[1] + scnt[2] + scnt[3];
        out[0] = (n > 0) ? s / (float)n : 0.0f;
    }
}

extern "C" void kernel_launch(void* const* d_in, const int* in_sizes, int n_in,
                              void* d_out, int out_size, void* d_ws, size_t ws_size,
                              hipStream_t stream) {
    const float* x = (const float*)d_in[0];
    const int* labels = (const int*)d_in[1];
    float* out = (float*)d_out;

    char* ws = (char*)d_ws;
    unsigned short* xb = (unsigned short*)ws;                       // 4096*2048*2 B
    float* sq = (float*)(ws + (size_t)NN * DD * 2);                 // 16 KB
    unsigned int* ap = (unsigned int*)(ws + (size_t)NN * DD * 2 + (size_t)NN * 4);
    unsigned int* an = (unsigned int*)(ws + (size_t)NN * DD * 2 + (size_t)NN * 8);

    prep_kernel<<<NN, 256, 0, stream>>>(x, xb, sq, ap, an);
    dim3 grid(32, 32);
    gemm_reduce_kernel<<<grid, 256, 0, stream>>>(xb, sq, labels, ap, an);
    finalize_kernel<<<1, 256, 0, stream>>>(ap, an, out);
}

// Round 2
// 174.005 us; speedup vs baseline: 1.1272x; 1.1272x over previous
//
#include <hip/hip_runtime.h>

#define NN 4096
#define DD 2048
#define MARGIN_F 0.3f

typedef __attribute__((ext_vector_type(8))) short bf16x8;
typedef __attribute__((ext_vector_type(4))) float f32x4;

__device__ __forceinline__ unsigned short f2bf(float f) {
    union { float f; unsigned u; } cv; cv.f = f;
    unsigned u = cv.u;
    return (unsigned short)((u + 0x7FFFu + ((u >> 16) & 1u)) >> 16);
}

// One block per row: fp32 sum-of-squares, bf16 copy of the row, init ap/an.
__global__ __launch_bounds__(256) void prep_kernel(const float* __restrict__ x,
                                                   unsigned short* __restrict__ xb,
                                                   float* __restrict__ sq,
                                                   unsigned int* __restrict__ ap,
                                                   unsigned int* __restrict__ an) {
    const int row = blockIdx.x;
    const int t = threadIdx.x;
    const float* xr = x + (size_t)row * DD;
    float4 v0 = ((const float4*)xr)[2 * t];
    float4 v1 = ((const float4*)xr)[2 * t + 1];
    float s = v0.x * v0.x + v0.y * v0.y + v0.z * v0.z + v0.w * v0.w +
              v1.x * v1.x + v1.y * v1.y + v1.z * v1.z + v1.w * v1.w;
    ushort4 o0, o1;
    o0.x = f2bf(v0.x); o0.y = f2bf(v0.y); o0.z = f2bf(v0.z); o0.w = f2bf(v0.w);
    o1.x = f2bf(v1.x); o1.y = f2bf(v1.y); o1.z = f2bf(v1.z); o1.w = f2bf(v1.w);
    ushort4* xo = (ushort4*)(xb + (size_t)row * DD);
    xo[2 * t] = o0;
    xo[2 * t + 1] = o1;

    for (int off = 32; off > 0; off >>= 1) s += __shfl_down(s, off, 64);
    __shared__ float wsum[4];
    const int wave = t >> 6, lane = t & 63;
    if (lane == 0) wsum[wave] = s;
    __syncthreads();
    if (t == 0) {
        sq[row] = wsum[0] + wsum[1] + wsum[2] + wsum[3];
        ap[row] = 0u;            // hardest-positive max starts at 0
        an[row] = 0x7F800000u;   // +inf
    }
}

// Symmetric batch-hard GEMM: only upper-triangular 128x128 block pairs
// (bi <= bj), 528 blocks. Off-diagonal blocks run a second, transposed
// epilogue so each ordered pair (i,j), i!=j is reduced exactly once.
// m97 structure: BK=32, global_load_lds w=16, 2x2 waves of 64x64, 4x4 frags.
__global__ __launch_bounds__(256) void gemm_reduce_kernel(
    const unsigned short* __restrict__ xb,
    const float* __restrict__ sq,
    const int* __restrict__ labels,
    unsigned int* __restrict__ ap,
    unsigned int* __restrict__ an) {
    __shared__ __align__(16) unsigned short As[128 * 32];
    __shared__ __align__(16) unsigned short Bs[128 * 32];

    // decode upper-triangular block pair (bi <= bj) from linear id
    int rem = blockIdx.x;
    int bi = 0;
    while (rem >= 32 - bi) { rem -= 32 - bi; ++bi; }
    const int bj = bi + rem;
    const int row0 = bi * 128;
    const int col0 = bj * 128;
    const bool offdiag = (bi != bj);

    const int t = threadIdx.x;
    const int lane = t & 63;
    const int wave = t >> 6;
    const int c = lane & 15;          // fragment column lane
    const int q = lane >> 4;          // quad id
    const int wr = (wave >> 1) * 64;  // wave row offset in tile
    const int wc = (wave & 1) * 64;   // wave col offset in tile

    f32x4 acc[4][4];
#pragma unroll
    for (int mi = 0; mi < 4; ++mi)
#pragma unroll
        for (int ni = 0; ni < 4; ++ni)
            acc[mi][ni] = (f32x4){0.f, 0.f, 0.f, 0.f};

    const int ca0 = t, ca1 = t + 256;
    const unsigned short* gA0 = xb + (size_t)(row0 + (ca0 >> 2)) * DD + (ca0 & 3) * 8;
    const unsigned short* gA1 = xb + (size_t)(row0 + (ca1 >> 2)) * DD + (ca1 & 3) * 8;
    const unsigned short* gB0 = xb + (size_t)(col0 + (ca0 >> 2)) * DD + (ca0 & 3) * 8;
    const unsigned short* gB1 = xb + (size_t)(col0 + (ca1 >> 2)) * DD + (ca1 & 3) * 8;
    unsigned short* lA0 = &As[ca0 * 8];
    unsigned short* lA1 = &As[ca1 * 8];
    unsigned short* lB0 = &Bs[ca0 * 8];
    unsigned short* lB1 = &Bs[ca1 * 8];

    for (int k0 = 0; k0 < DD; k0 += 32) {
        __builtin_amdgcn_global_load_lds(
            (const __attribute__((address_space(1))) void*)(gA0 + k0),
            (__attribute__((address_space(3))) void*)lA0, 16, 0, 0);
        __builtin_amdgcn_global_load_lds(
            (const __attribute__((address_space(1))) void*)(gA1 + k0),
            (__attribute__((address_space(3))) void*)lA1, 16, 0, 0);
        __builtin_amdgcn_global_load_lds(
            (const __attribute__((address_space(1))) void*)(gB0 + k0),
            (__attribute__((address_space(3))) void*)lB0, 16, 0, 0);
        __builtin_amdgcn_global_load_lds(
            (const __attribute__((address_space(1))) void*)(gB1 + k0),
            (__attribute__((address_space(3))) void*)lB1, 16, 0, 0);
        __syncthreads();

        const bf16x8* Av = (const bf16x8*)As;
        const bf16x8* Bv = (const bf16x8*)Bs;
        bf16x8 af[4], bfr[4];
#pragma unroll
        for (int mi = 0; mi < 4; ++mi) af[mi] = Av[(wr + mi * 16 + c) * 4 + q];
#pragma unroll
        for (int ni = 0; ni < 4; ++ni) bfr[ni] = Bv[(wc + ni * 16 + c) * 4 + q];
#pragma unroll
        for (int mi = 0; mi < 4; ++mi)
#pragma unroll
            for (int ni = 0; ni < 4; ++ni)
                acc[mi][ni] = __builtin_amdgcn_mfma_f32_16x16x32_bf16(
                    af[mi], bfr[ni], acc[mi][ni], 0, 0, 0);
        __syncthreads();
    }

    // --- Epilogue ---
    // C/D layout: col = lane&15 (c), row = q*4 + reg  [m89/m91 verified]
    float sq_col[4];
    int lab_col[4];
#pragma unroll
    for (int ni = 0; ni < 4; ++ni) {
        const int gj = col0 + wc + ni * 16 + c;
        sq_col[ni] = sq[gj];
        lab_col[ni] = labels[gj];
    }
    int lab_row[4][4];
    // convert dot -> dist in place
#pragma unroll
    for (int mi = 0; mi < 4; ++mi) {
#pragma unroll
        for (int r = 0; r < 4; ++r) {
            const int gi = row0 + wr + mi * 16 + q * 4 + r;
            const float sqi = sq[gi];
            lab_row[mi][r] = labels[gi];
#pragma unroll
            for (int ni = 0; ni < 4; ++ni) {
                float d2 = sqi + sq_col[ni] - 2.0f * acc[mi][ni][r];
                acc[mi][ni][r] = sqrtf(fmaxf(d2, 0.0f));
            }
        }
    }

    // Row-side reduction: rows gi vs this tile's 128 columns.
#pragma unroll
    for (int mi = 0; mi < 4; ++mi) {
#pragma unroll
        for (int r = 0; r < 4; ++r) {
            const int gi = row0 + wr + mi * 16 + q * 4 + r;
            const int li = lab_row[mi][r];
            float apm = 0.0f;
            float anm = __builtin_inff();
#pragma unroll
            for (int ni = 0; ni < 4; ++ni) {
                const int gj = col0 + wc + ni * 16 + c;
                const float dist = acc[mi][ni][r];
                if (li == lab_col[ni]) {
                    if (gi != gj) apm = fmaxf(apm, dist);  // exclude diagonal
                } else {
                    anm = fminf(anm, dist);
                }
            }
#pragma unroll
            for (int off = 1; off < 16; off <<= 1) {
                apm = fmaxf(apm, __shfl_xor(apm, off, 16));
                anm = fminf(anm, __shfl_xor(anm, off, 16));
            }
            if (c == 0) {
                atomicMax(&ap[gi], __float_as_uint(apm));
                atomicMin(&an[gi], __float_as_uint(anm));
            }
        }
    }

    // Column-side (transposed) reduction, off-diagonal blocks only:
    // S(gi,gj) also serves row gj with partner gi (symmetry). gi != gj always.
    if (offdiag) {
#pragma unroll
        for (int ni = 0; ni < 4; ++ni) {
            const int gj = col0 + wc + ni * 16 + c;
            const int lj = lab_col[ni];
            float apm = 0.0f;
            float anm = __builtin_inff();
#pragma unroll
            for (int mi = 0; mi < 4; ++mi) {
#pragma unroll
                for (int r = 0; r < 4; ++r) {
                    const float dist = acc[mi][ni][r];
                    if (lj == lab_row[mi][r]) {
                        apm = fmaxf(apm, dist);
                    } else {
                        anm = fminf(anm, dist);
                    }
                }
            }
            // fold across the 4 quads holding this column (lane bits 4-5)
            apm = fmaxf(apm, __shfl_xor(apm, 16, 64));
            anm = fminf(anm, __shfl_xor(anm, 16, 64));
            apm = fmaxf(apm, __shfl_xor(apm, 32, 64));
            anm = fminf(anm, __shfl_xor(anm, 32, 64));
            if (q == 0) {
                atomicMax(&ap[gj], __float_as_uint(apm));
                atomicMin(&an[gj], __float_as_uint(anm));
            }
        }
    }
}

__global__ __launch_bounds__(256) void finalize_kernel(const unsigned int* __restrict__ ap,
                                                       const unsigned int* __restrict__ an,
                                                       float* __restrict__ out) {
    float sum = 0.0f;
    int cnt = 0;
    for (int i = threadIdx.x; i < NN; i += 256) {
        const float a = __uint_as_float(ap[i]);
        const float b = __uint_as_float(an[i]);
        if ((a > 0.0f) && (b < __builtin_inff())) {
            sum += fmaxf(a - b + MARGIN_F, 0.0f);
            cnt += 1;
        }
    }
    for (int off = 32; off > 0; off >>= 1) {
        sum += __shfl_down(sum, off, 64);
        cnt += __shfl_down(cnt, off, 64);
    }
    __shared__ float ssum[4];
    __shared__ int scnt[4];
    const int wave = threadIdx.x >> 6, lane = threadIdx.x & 63;
    if (lane == 0) { ssum[wave] = sum; scnt[wave] = cnt; }
    __syncthreads();
    if (threadIdx.x == 0) {
        float s = ssum[0] + ssum[1] + ssum[2] + ssum[3];
        int n = scnt[0] + scnt[1] + scnt[2] + scnt[3];
        out[0] = (n > 0) ? s / (float)n : 0.0f;
    }
}

extern "C" void kernel_launch(void* const* d_in, const int* in_sizes, int n_in,
                              void* d_out, int out_size, void* d_ws, size_t ws_size,
                              hipStream_t stream) {
    const float* x = (const float*)d_in[0];
    const int* labels = (const int*)d_in[1];
    float* out = (float*)d_out;

    char* ws = (char*)d_ws;
    unsigned short* xb = (unsigned short*)ws;                       // 4096*2048*2 B
    float* sq = (float*)(ws + (size_t)NN * DD * 2);
    unsigned int* ap = (unsigned int*)(ws + (size_t)NN * DD * 2 + (size_t)NN * 4);
    unsigned int* an = (unsigned int*)(ws + (size_t)NN * DD * 2 + (size_t)NN * 8);

    prep_kernel<<<NN, 256, 0, stream>>>(x, xb, sq, ap, an);
    gemm_reduce_kernel<<<528, 256, 0, stream>>>(xb, sq, labels, ap, an);
    finalize_kernel<<<1, 256, 0, stream>>>(ap, an, out);
}